// Round 1
// baseline (299.708 us; speedup 1.0000x reference)
//
#include <hip/hip_runtime.h>
#include <stdint.h>

#define DEV __device__ __forceinline__

typedef __attribute__((ext_vector_type(8))) short bf16x8;
typedef __attribute__((ext_vector_type(4))) float f32x4;

DEV ushort f2bf(float f) {
  union { float f; uint32_t u; } c; c.f = f;
  return (ushort)((c.u + 0x7FFFu + ((c.u >> 16) & 1)) >> 16);
}

// ---------------- transpose f32 [R][C] -> bf16 [C][R] ----------------
__global__ __launch_bounds__(256) void k_transpose_bf(const float* __restrict__ in,
                                                      ushort* __restrict__ out,
                                                      int R, int C) {
  __shared__ float t[32][33];
  int tx = threadIdx.x & 31, ty = threadIdx.x >> 5;
  int c0 = blockIdx.x * 32, r0 = blockIdx.y * 32;
#pragma unroll
  for (int k = 0; k < 4; ++k)
    t[ty + 8 * k][tx] = in[(size_t)(r0 + ty + 8 * k) * C + c0 + tx];
  __syncthreads();
#pragma unroll
  for (int k = 0; k < 4; ++k)
    out[(size_t)(c0 + ty + 8 * k) * R + r0 + tx] = f2bf(t[tx][ty + 8 * k]);
}

// ---------------- elementwise f32 -> bf16 ----------------
__global__ __launch_bounds__(256) void k_cvt_bf(const float* __restrict__ in,
                                                ushort* __restrict__ out, int n4) {
  int i = blockIdx.x * 256 + threadIdx.x;
  if (i >= n4) return;
  float4 v = reinterpret_cast<const float4*>(in)[i];
  ushort4 o; o.x = f2bf(v.x); o.y = f2bf(v.y); o.z = f2bf(v.z); o.w = f2bf(v.w);
  reinterpret_cast<ushort4*>(out)[i] = o;
}

// ---------------- layernorm: f32 [4096][512] -> bf16 ----------------
__global__ __launch_bounds__(64) void k_ln(const float* __restrict__ x,
                                           const float* __restrict__ g,
                                           const float* __restrict__ be,
                                           ushort* __restrict__ out) {
  int row = blockIdx.x, lane = threadIdx.x;
  const float* xr = x + (size_t)row * 512 + lane * 8;
  float4 a = *reinterpret_cast<const float4*>(xr);
  float4 b = *reinterpret_cast<const float4*>(xr + 4);
  float xs[8] = {a.x, a.y, a.z, a.w, b.x, b.y, b.z, b.w};
  float s = 0.f, q = 0.f;
#pragma unroll
  for (int i = 0; i < 8; ++i) { s += xs[i]; q += xs[i] * xs[i]; }
#pragma unroll
  for (int off = 32; off; off >>= 1) { s += __shfl_xor(s, off); q += __shfl_xor(q, off); }
  float mu = s * (1.f / 512.f);
  float var = q * (1.f / 512.f) - mu * mu;
  float inv = rsqrtf(var + 1e-5f);
  const float* gp = g + lane * 8;
  const float* bp = be + lane * 8;
  ushort o[8];
#pragma unroll
  for (int i = 0; i < 8; ++i) o[i] = f2bf((xs[i] - mu) * inv * gp[i] + bp[i]);
  *reinterpret_cast<uint4*>(out + (size_t)row * 512 + lane * 8) = *reinterpret_cast<uint4*>(o);
}

// ---------------- GEMM: C[M][N] = A[M][K] @ Bt[N][K]^T + epilogue ----------------
// EPI 0: qkv split -> q_bf (bf16) + present (f32)
// EPI 1: + bias + res (f32) -> outf (f32)
// EPI 2: gelu(bias+acc) -> outb (bf16)
template <int EPI>
__global__ __launch_bounds__(256) void k_gemm(
    const ushort* __restrict__ A, const ushort* __restrict__ Bt,
    int M, int N, int K,
    const float* __restrict__ bias, const float* __restrict__ res,
    float* __restrict__ outf, ushort* __restrict__ outb,
    float* __restrict__ present, ushort* __restrict__ qbf) {
  __shared__ ushort As[128][72];
  __shared__ ushort Bs[128][72];
  const int tid = threadIdx.x, lane = tid & 63, w = tid >> 6;
  const int g = lane >> 4, l16 = lane & 15;
  const int m0 = blockIdx.y * 128, n0 = blockIdx.x * 128;
  const int wm = (w >> 1) * 64, wn = (w & 1) * 64;
  f32x4 acc[4][4];
#pragma unroll
  for (int i = 0; i < 4; ++i)
#pragma unroll
    for (int j = 0; j < 4; ++j) acc[i][j] = (f32x4){0.f, 0.f, 0.f, 0.f};

  for (int k0 = 0; k0 < K; k0 += 64) {
#pragma unroll
    for (int c = 0; c < 4; ++c) {
      int cc = tid + 256 * c;
      int r = cc >> 3, k8 = (cc & 7) << 3;
      *reinterpret_cast<uint4*>(&As[r][k8]) =
          *reinterpret_cast<const uint4*>(&A[(size_t)(m0 + r) * K + k0 + k8]);
      *reinterpret_cast<uint4*>(&Bs[r][k8]) =
          *reinterpret_cast<const uint4*>(&Bt[(size_t)(n0 + r) * K + k0 + k8]);
    }
    __syncthreads();
#pragma unroll
    for (int kk = 0; kk < 2; ++kk) {
      bf16x8 af[4], bfr[4];
#pragma unroll
      for (int f = 0; f < 4; ++f) {
        af[f] = *reinterpret_cast<const bf16x8*>(&As[wm + f * 16 + l16][kk * 32 + g * 8]);
        bfr[f] = *reinterpret_cast<const bf16x8*>(&Bs[wn + f * 16 + l16][kk * 32 + g * 8]);
      }
#pragma unroll
      for (int i = 0; i < 4; ++i)
#pragma unroll
        for (int j = 0; j < 4; ++j)
          acc[i][j] = __builtin_amdgcn_mfma_f32_16x16x32_bf16(af[i], bfr[j], acc[i][j], 0, 0, 0);
    }
    __syncthreads();
  }

#pragma unroll
  for (int i = 0; i < 4; ++i)
#pragma unroll
    for (int j = 0; j < 4; ++j)
#pragma unroll
      for (int r = 0; r < 4; ++r) {
        int row = m0 + wm + i * 16 + g * 4 + r;
        int col = n0 + wn + j * 16 + l16;
        float v = acc[i][j][r] + bias[col];
        if constexpr (EPI == 0) {
          int third = col >> 9, hh = (col >> 6) & 7, d = col & 63;
          int bb = row >> 11, sq = row & 2047;
          if (third == 0) {
            qbf[((((size_t)bb * 8 + hh) * 2048) + sq) * 64 + d] = f2bf(v);
          } else {
            present[((((size_t)bb * 2 + (third - 1)) * 8 + hh) * 2048 + sq) * 64 + d] = v;
          }
        } else if constexpr (EPI == 1) {
          size_t idx = (size_t)row * N + col;
          outf[idx] = v + res[idx];
        } else {
          float u = 0.7978845608f * (v + 0.044715f * v * v * v);
          float e = __expf(2.f * u);
          float th = 1.f - 2.f / (e + 1.f);
          outb[(size_t)row * N + col] = f2bf(0.5f * v * (1.f + th));
        }
      }
}

// ---------------- fused causal attention with skewed relative logits ----------------
// grid (16 pairs, 16 bh), block 256. Each block does q-tiles (t, 31-t) of 64 rows.
__global__ __launch_bounds__(256) void k_attn(
    const ushort* __restrict__ qbf, const float* __restrict__ present,
    const ushort* __restrict__ Ebf, ushort* __restrict__ attb) {
  constexpr int S = 2048;
  __shared__ ushort Ks[64][72];
  __shared__ ushort Vt[64][72];
  __shared__ ushort Es[128][72];
  __shared__ float Rs[4][16][80];
  __shared__ ushort Ps[4][16][72];
  const int tid = threadIdx.x, lane = tid & 63, w = tid >> 6;
  const int g = lane >> 4, l16 = lane & 15;
  const int bh = blockIdx.y, b = bh >> 3, h = bh & 7;
  const float* kp = present + (((size_t)b * 2 + 0) * 8 + h) * S * 64;
  const float* vp = present + (((size_t)b * 2 + 1) * 8 + h) * S * 64;
  const ushort* qp = qbf + (size_t)bh * S * 64;
  const ushort* ep = Ebf + (size_t)h * S * 64;

  for (int half = 0; half < 2; ++half) {
    const int qt = half ? 31 - (int)blockIdx.x : (int)blockIdx.x;
    const int i0 = qt * 64;
    const int iw = i0 + w * 16;
    bf16x8 qf[2];
#pragma unroll
    for (int kk = 0; kk < 2; ++kk)
      qf[kk] = *reinterpret_cast<const bf16x8*>(&qp[(size_t)(iw + l16) * 64 + kk * 32 + g * 8]);
    f32x4 o[4];
#pragma unroll
    for (int fv = 0; fv < 4; ++fv) o[fv] = (f32x4){0.f, 0.f, 0.f, 0.f};
    float mrun[4], lrun[4];
#pragma unroll
    for (int r = 0; r < 4; ++r) { mrun[r] = -1e30f; lrun[r] = 0.f; }

    const int nkt = qt + 1;
    for (int kt = 0; kt < nkt; ++kt) {
      const int j0 = kt * 64;
      // stage K (row-major) and V^T
#pragma unroll
      for (int c = 0; c < 4; ++c) {
        int cc = tid + 256 * c;
        int j = cc >> 4, d4 = (cc & 15) << 2;
        float4 kv = *reinterpret_cast<const float4*>(&kp[(size_t)(j0 + j) * 64 + d4]);
        ushort4 kb; kb.x = f2bf(kv.x); kb.y = f2bf(kv.y); kb.z = f2bf(kv.z); kb.w = f2bf(kv.w);
        *reinterpret_cast<ushort4*>(&Ks[j][d4]) = kb;
        float4 vv = *reinterpret_cast<const float4*>(&vp[(size_t)(j0 + j) * 64 + d4]);
        Vt[d4 + 0][j] = f2bf(vv.x); Vt[d4 + 1][j] = f2bf(vv.y);
        Vt[d4 + 2][j] = f2bf(vv.z); Vt[d4 + 3][j] = f2bf(vv.w);
      }
      // stage E band: rows t=0..127 hold E[BS+t] (clamped)
      const int BS = S - 64 - i0 + j0;
#pragma unroll
      for (int c = 0; c < 4; ++c) {
        int cc = tid + 256 * c;
        int t = cc >> 3, k8 = (cc & 7) << 3;
        int l = BS + t; if (l > S - 1) l = S - 1;
        *reinterpret_cast<uint4*>(&Es[t][k8]) =
            *reinterpret_cast<const uint4*>(&ep[(size_t)l * 64 + k8]);
      }
      __syncthreads();

      // QK^T
      f32x4 sacc[4];
#pragma unroll
      for (int fn = 0; fn < 4; ++fn) sacc[fn] = (f32x4){0.f, 0.f, 0.f, 0.f};
#pragma unroll
      for (int kk = 0; kk < 2; ++kk)
#pragma unroll
        for (int fn = 0; fn < 4; ++fn) {
          bf16x8 kf = *reinterpret_cast<const bf16x8*>(&Ks[fn * 16 + l16][kk * 32 + g * 8]);
          sacc[fn] = __builtin_amdgcn_mfma_f32_16x16x32_bf16(qf[kk], kf, sacc[fn], 0, 0, 0);
        }
      // REL band: wave w covers t_full in [tb, tb+79]
      const int tb = 48 - 16 * w;
      f32x4 racc[5];
#pragma unroll
      for (int fc = 0; fc < 5; ++fc) racc[fc] = (f32x4){0.f, 0.f, 0.f, 0.f};
#pragma unroll
      for (int kk = 0; kk < 2; ++kk)
#pragma unroll
        for (int fc = 0; fc < 5; ++fc) {
          bf16x8 ef = *reinterpret_cast<const bf16x8*>(&Es[tb + fc * 16 + l16][kk * 32 + g * 8]);
          racc[fc] = __builtin_amdgcn_mfma_f32_16x16x32_bf16(qf[kk], ef, racc[fc], 0, 0, 0);
        }
#pragma unroll
      for (int fc = 0; fc < 5; ++fc)
#pragma unroll
        for (int r = 0; r < 4; ++r)
          Rs[w][g * 4 + r][fc * 16 + l16] = racc[fc][r];

      // S assembly + skew gather + mask + online softmax
      float Sv[4][4], mtile[4];
#pragma unroll
      for (int r = 0; r < 4; ++r) mtile[r] = -1e30f;
#pragma unroll
      for (int fn = 0; fn < 4; ++fn)
#pragma unroll
        for (int r = 0; r < 4; ++r) {
          int dil = g * 4 + r, dj = fn * 16 + l16;
          float sv = (sacc[fn][r] + Rs[w][dil][15 - dil + dj]) * 0.125f;
          if (j0 + dj > iw + dil) sv = -1e30f;
          Sv[fn][r] = sv;
          mtile[r] = fmaxf(mtile[r], sv);
        }
#pragma unroll
      for (int off = 1; off < 16; off <<= 1)
#pragma unroll
        for (int r = 0; r < 4; ++r) mtile[r] = fmaxf(mtile[r], __shfl_xor(mtile[r], off));
      float corr[4], psum[4];
#pragma unroll
      for (int r = 0; r < 4; ++r) {
        float mn = fmaxf(mrun[r], mtile[r]);
        corr[r] = __expf(mrun[r] - mn);
        mrun[r] = mn;
        psum[r] = 0.f;
      }
#pragma unroll
      for (int fn = 0; fn < 4; ++fn)
#pragma unroll
        for (int r = 0; r < 4; ++r) {
          float p = __expf(Sv[fn][r] - mrun[r]);
          psum[r] += p;
          Ps[w][g * 4 + r][fn * 16 + l16] = f2bf(p);
        }
#pragma unroll
      for (int off = 1; off < 16; off <<= 1)
#pragma unroll
        for (int r = 0; r < 4; ++r) psum[r] += __shfl_xor(psum[r], off);
#pragma unroll
      for (int r = 0; r < 4; ++r) lrun[r] = lrun[r] * corr[r] + psum[r];
#pragma unroll
      for (int fv = 0; fv < 4; ++fv)
#pragma unroll
        for (int r = 0; r < 4; ++r) o[fv][r] *= corr[r];

      // PV
#pragma unroll
      for (int kk = 0; kk < 2; ++kk) {
        bf16x8 pf = *reinterpret_cast<const bf16x8*>(&Ps[w][l16][kk * 32 + g * 8]);
#pragma unroll
        for (int fv = 0; fv < 4; ++fv) {
          bf16x8 vf = *reinterpret_cast<const bf16x8*>(&Vt[fv * 16 + l16][kk * 32 + g * 8]);
          o[fv] = __builtin_amdgcn_mfma_f32_16x16x32_bf16(pf, vf, o[fv], 0, 0, 0);
        }
      }
      __syncthreads();
    }
    // epilogue: att[b*S+i][h*64+dv] bf16
#pragma unroll
    for (int fv = 0; fv < 4; ++fv)
#pragma unroll
      for (int r = 0; r < 4; ++r) {
        int dil = g * 4 + r;
        float v = o[fv][r] / lrun[r];
        attb[(size_t)(b * S + iw + dil) * 512 + h * 64 + fv * 16 + l16] = f2bf(v);
      }
  }
}

extern "C" void kernel_launch(void* const* d_in, const int* in_sizes, int n_in,
                              void* d_out, int out_size, void* d_ws, size_t ws_size,
                              hipStream_t stream) {
  const float* x = (const float*)d_in[0];
  // d_in[1] = mask (pure causal; implemented directly)
  const float* W_qkv = (const float*)d_in[2];
  const float* b_qkv = (const float*)d_in[3];
  const float* W_proj = (const float*)d_in[4];
  const float* b_proj = (const float*)d_in[5];
  const float* E = (const float*)d_in[6];
  const float* g1 = (const float*)d_in[7];
  const float* be1 = (const float*)d_in[8];
  const float* g2 = (const float*)d_in[9];
  const float* be2 = (const float*)d_in[10];
  const float* W_fc1 = (const float*)d_in[11];
  const float* b_fc1 = (const float*)d_in[12];
  const float* W_fc2 = (const float*)d_in[13];
  const float* b_fc2 = (const float*)d_in[14];

  float* x_out = (float*)d_out;                 // 2*2048*512 f32
  float* present = x_out + 2097152;             // (2,2,8,2048,64) f32

  char* ws = (char*)d_ws;
  ushort* a_bf   = (ushort*)(ws + 0);           // 4096x512 bf16
  ushort* m_bf   = (ushort*)(ws + 4194304);     // 4096x512 bf16
  ushort* q_bf   = (ushort*)(ws + 8388608);     // [b][h][s][64] bf16
  ushort* att_bf = (ushort*)(ws + 12582912);    // 4096x512 bf16
  ushort* h_bf   = (ushort*)(ws + 16777216);    // 4096x2048 bf16
  float*  x2     = (float*)(ws + 33554432);     // 4096x512 f32
  ushort* Wqkv_t = (ushort*)(ws + 41943040);    // 1536x512 bf16
  ushort* Wproj_t= (ushort*)(ws + 43515904);    // 512x512 bf16
  ushort* Wfc1_t = (ushort*)(ws + 44040192);    // 2048x512 bf16
  ushort* Wfc2_t = (ushort*)(ws + 46137344);    // 512x2048 bf16
  ushort* E_bf   = (ushort*)(ws + 48234496);    // 8x2048x64 bf16

  k_transpose_bf<<<dim3(48, 16), 256, 0, stream>>>(W_qkv, Wqkv_t, 512, 1536);
  k_transpose_bf<<<dim3(16, 16), 256, 0, stream>>>(W_proj, Wproj_t, 512, 512);
  k_transpose_bf<<<dim3(64, 16), 256, 0, stream>>>(W_fc1, Wfc1_t, 512, 2048);
  k_transpose_bf<<<dim3(16, 64), 256, 0, stream>>>(W_fc2, Wfc2_t, 2048, 512);
  k_cvt_bf<<<1024, 256, 0, stream>>>(E, E_bf, 262144);
  k_ln<<<4096, 64, 0, stream>>>(x, g1, be1, a_bf);
  k_gemm<0><<<dim3(12, 32), 256, 0, stream>>>(a_bf, Wqkv_t, 4096, 1536, 512,
                                              b_qkv, nullptr, nullptr, nullptr, present, q_bf);
  k_attn<<<dim3(16, 16), 256, 0, stream>>>(q_bf, present, E_bf, att_bf);
  k_gemm<1><<<dim3(4, 32), 256, 0, stream>>>(att_bf, Wproj_t, 4096, 512, 512,
                                             b_proj, x, x2, nullptr, nullptr, nullptr);
  k_ln<<<4096, 64, 0, stream>>>(x2, g2, be2, m_bf);
  k_gemm<2><<<dim3(16, 32), 256, 0, stream>>>(m_bf, Wfc1_t, 4096, 2048, 512,
                                              b_fc1, nullptr, nullptr, h_bf, nullptr, nullptr);
  k_gemm<1><<<dim3(4, 32), 256, 0, stream>>>(h_bf, Wfc2_t, 4096, 512, 2048,
                                             b_fc2, x2, x_out, nullptr, nullptr, nullptr);
}